// Round 5
// baseline (100.124 us; speedup 1.0000x reference)
//
#include <hip/hip_runtime.h>

#define HH 80
#define WW 80
#define IMG (HH * WW)             // 6400
#define NV ((HH - 1) * WW)        // 6320 vertical edge slots
#define NPTS (NV + HH * (WW - 1)) // 12640 edge slots per image
#define NPIX (2 * IMG)            // 12800
#define BIGF 1.0e10f
#define INVC 1.0e7f
#define EPSF 1e-8f
#define QSCALE 131072.0f          // 2^17 fixed-point scale (exact-commutative sums)

#define NB 256                    // grid blocks for both kernels
#define APT 8                     // A points per thread in min phase
#define NSLICE 16
#define MAXPAIR 396               // max B-pairs per tile (slicelen<=790 -> 395)

// padded extraction space: 12672 = 198 waves of 64 per set
#define SETPAD 12672
#define EXWAVES (4 * (SETPAD / 64))   // 792
#define PXWAVES (NPIX / 64)           // 200

typedef float f32x2 __attribute__((ext_vector_type(2)));

__device__ __forceinline__ long long wave_reduce_ll(long long v) {
#pragma unroll
  for (int o = 32; o > 0; o >>= 1) {
    int2 p = *(int2*)&v;
    p.x = __shfl_down(p.x, o, 64);
    p.y = __shfl_down(p.y, o, 64);
    v += *(long long*)&p;
  }
  return v;
}

// --------------------------------------------------------------- k_prep
// 256 blocks. minarr init + pixel loss (int64 fixed point) + zero-crossing
// extraction with wave-ballot atomic append (order non-deterministic, but all
// downstream consumers are order-invariant and exact -> output bitwise stable).
// cnt / pix_i are pre-zeroed by the memset node.
__global__ void __launch_bounds__(256) k_prep(
    const float* __restrict__ pred, const float* __restrict__ gt,
    float2* __restrict__ pts, float* __restrict__ minarr,
    int* __restrict__ cnt, unsigned long long* __restrict__ pix_i) {
  int tid = threadIdx.x, lane = tid & 63, wid = tid >> 6;
  int gtid = blockIdx.x * 256 + tid;

  if (gtid < 4 * NPTS) minarr[gtid] = BIGF;

  int gw = blockIdx.x * 4 + wid;
  if (gw < EXWAVES) {
    int set = gw / (SETPAD / 64);
    int idx = (gw - set * (SETPAD / 64)) * 64 + lane;
    const float* s = (set < 2 ? pred : gt) + (set & 1) * IMG;
    float r = 0.f, c = 0.f;
    bool valid = false;
    if (idx < NPTS) {
      if (idx < NV) {
        int i = idx / WW, j = idx - i * WW;
        float v1 = s[i * WW + j], v2 = s[(i + 1) * WW + j];
        c = (float)j;
        if (v1 == 0.f)      { r = (float)i;       valid = true; }
        else if (v2 == 0.f) { r = (float)i + 1.f; valid = true; }
        else {
          r = (float)i + fabsf(v1) / (fabsf(v1) + fabsf(v2) + EPSF);
          valid = (v1 * v2 < 0.f);
        }
      } else {
        int t = idx - NV;
        int i = t / (WW - 1), j = t - i * (WW - 1);
        float h1 = s[i * WW + j], h2 = s[i * WW + j + 1];
        r = (float)i;
        if (h1 == 0.f)      { c = (float)j;       valid = true; }
        else if (h2 == 0.f) { c = (float)j + 1.f; valid = true; }
        else {
          c = (float)j + fabsf(h1) / (fabsf(h1) + fabsf(h2) + EPSF);
          valid = (h1 * h2 < 0.f);
        }
      }
    }
    unsigned long long mask = __ballot(valid);
    int nw = __popcll(mask);
    int base = 0;
    if (lane == 0 && nw) base = atomicAdd(&cnt[set], nw);
    base = __shfl(base, 0, 64);
    if (valid) {
      int lpos = __popcll(mask & ((1ull << lane) - 1ull));
      pts[set * NPTS + base + lpos] = make_float2(r, c);
    }
  } else if (gw < EXWAVES + PXWAVES) {
    int p = (gw - EXWAVES) * 64 + lane;
    float d = fabsf(pred[p] - gt[p]);
    long long q = (long long)(d * QSCALE + 0.5f);
    q = wave_reduce_ll(q);
    if (lane == 0) atomicAdd(pix_i, (unsigned long long)q);
  }
}

// --------------------------------------------------------------- k_minfin
// dir 0: A=0 B=2 | 1: A=2 B=0 | 2: A=1 B=3 | 3: A=3 B=1
// min over b of (q2 - 2px*qx - 2py*qy) via packed v_pk_fma_f32 (2 B/instr);
// +p2 and sqrt are monotone. Ticket lights-out: last block sums + writes out.
__global__ void __launch_bounds__(256) k_minfin(
    const float2* __restrict__ pts, float* __restrict__ minarr,
    const int* __restrict__ cnt, const unsigned long long* __restrict__ pix_i,
    unsigned int* __restrict__ ticket, float* __restrict__ out) {
  __shared__ f32x2 qx_s[MAXPAIR], qy_s[MAXPAIR], q2_s[MAXPAIR];
  __shared__ long long red_s[4];
  __shared__ int fin_s;
  int tid = threadIdx.x, lane = tid & 63, wid = tid >> 6;

  int cntv[4] = {cnt[0], cnt[1], cnt[2], cnt[3]};
  int maxc = max(max(cntv[0], cntv[1]), max(cntv[2], cntv[3]));
  int abr = (maxc + 256 * APT - 1) / (256 * APT);
  if (abr < 1) abr = 1;
  int nwork = 4 * NSLICE * abr;

  for (int w = blockIdx.x; w < nwork; w += NB) {
    int dir = w & 3;
    int r = w >> 2;
    int achunk = r % abr, slice = r / abr;
    int Aset = ((dir & 1) << 1) | (dir >> 1);
    int Bset = Aset ^ 2;
    int cA = cntv[Aset], cB = cntv[Bset];
    int abase0 = achunk * (256 * APT);
    int slicelen = (((cB + NSLICE - 1) / NSLICE) + 1) & ~1;
    int b0 = slice * slicelen;
    int n = min(slicelen, cB - b0);
    if (abase0 < cA && n > 0) {   // block-uniform condition
      int sn = (n + 1) & ~1;
      for (int i = tid; i < sn; i += 256) {
        float2 q = (i < n) ? pts[Bset * NPTS + b0 + i] : make_float2(INVC, INVC);
        ((float*)qx_s)[i] = q.x;
        ((float*)qy_s)[i] = q.y;
        ((float*)q2_s)[i] = fmaf(q.x, q.x, q.y * q.y);
      }
      __syncthreads();

      int abase = abase0 + tid;
      f32x2 nxv[APT], nyv[APT];
      float p2v[APT], mv[APT];
#pragma unroll
      for (int i = 0; i < APT; ++i) {
        int a = abase + i * 256;
        float2 p = (a < cA) ? pts[Aset * NPTS + a] : make_float2(0.f, 0.f);
        f32x2 vx, vy;
        vx.x = vx.y = -2.f * p.x;
        vy.x = vy.y = -2.f * p.y;
        nxv[i] = vx; nyv[i] = vy;
        p2v[i] = fmaf(p.x, p.x, p.y * p.y);
        mv[i] = 3.0e38f;
      }

      int np2 = sn >> 1;
#pragma unroll 2
      for (int p = 0; p < np2; ++p) {
        f32x2 qx = qx_s[p], qy = qy_s[p], q2 = q2_s[p];
#pragma unroll
        for (int i = 0; i < APT; ++i) {
          f32x2 t, u;
          asm("v_pk_fma_f32 %0, %1, %2, %3" : "=v"(t) : "v"(nyv[i]), "v"(qy), "v"(q2));
          asm("v_pk_fma_f32 %0, %1, %2, %3" : "=v"(u) : "v"(nxv[i]), "v"(qx), "v"(t));
          mv[i] = fminf(fminf(u.x, u.y), mv[i]);  // -> v_min3_f32
        }
      }

#pragma unroll
      for (int i = 0; i < APT; ++i) {
        int a = abase + i * 256;
        if (a < cA) {
          float d2 = fmaxf(mv[i] + p2v[i], 0.f);
          // non-negative floats order as uint bit patterns; min is order-exact
          atomicMin((unsigned int*)&minarr[Aset * NPTS + a], __float_as_uint(d2));
        }
      }
      __syncthreads();
    }
  }

  // ---- ticket lights-out
  __threadfence();
  __syncthreads();
  if (tid == 0) {
    unsigned int t = __hip_atomic_fetch_add(ticket, 1u, __ATOMIC_ACQ_REL,
                                            __HIP_MEMORY_SCOPE_AGENT);
    fin_s = (t == NB - 1) ? 1 : 0;
  }
  __syncthreads();
  if (!fin_s) return;

  // ---- final block: exact int64 sums of round(sqrt(d2)*2^17), then combine
  long long tot[4];
  for (int set = 0; set < 4; ++set) {
    int nset = cntv[set];
    long long s = 0;
    for (int i = tid; i < nset; i += 256) {
      float d2 = __hip_atomic_load(&minarr[set * NPTS + i], __ATOMIC_RELAXED,
                                   __HIP_MEMORY_SCOPE_AGENT);
      s += (long long)(sqrtf(d2) * QSCALE + 0.5f);
    }
    s = wave_reduce_ll(s);
    if (lane == 0) red_s[wid] = s;
    __syncthreads();
    if (tid == 0) tot[set] = red_s[0] + red_s[1] + red_s[2] + red_s[3];
    __syncthreads();
  }
  if (tid == 0) {
    const float iq = 1.0f / QSCALE;
    float ss0 = (float)tot[0] * iq, ss1 = (float)tot[1] * iq;
    float ss2 = (float)tot[2] * iq, ss3 = (float)tot[3] * iq;
    float n0 = fmaxf((float)cntv[0], 1.f), n1 = fmaxf((float)cntv[1], 1.f);
    float n2 = fmaxf((float)cntv[2], 1.f), n3 = fmaxf((float)cntv[3], 1.f);
    float ch0 = -ss0 / n0 + ss2 / n2;
    float ch1 = -ss1 / n1 + ss3 / n3;
    out[0] = (float)(long long)(*pix_i) * iq / (float)NPIX;
    out[1] = 0.5f * (ch0 + ch1);
  }
}

extern "C" void kernel_launch(void* const* d_in, const int* in_sizes, int n_in,
                              void* d_out, int out_size, void* d_ws, size_t ws_size,
                              hipStream_t stream) {
  const float* pred = (const float*)d_in[0];
  const float* gt   = (const float*)d_in[1];
  float* out = (float*)d_out;

  // ws: [0..255] scalars (memset to 0 each call) | 4*NPTS float2 pts | 4*NPTS float mins
  int* cnt = (int*)d_ws;                                       // @0: cnt[4]
  unsigned int* ticket = (unsigned int*)((char*)d_ws + 16);    // @16
  unsigned long long* pix_i = (unsigned long long*)((char*)d_ws + 24); // @24
  float2* pts   = (float2*)((char*)d_ws + 256);
  float* minarr = (float*)((char*)d_ws + 256 + sizeof(float2) * 4 * NPTS);

  hipMemsetAsync(d_ws, 0, 256, stream);
  k_prep<<<NB, 256, 0, stream>>>(pred, gt, pts, minarr, cnt, pix_i);
  k_minfin<<<NB, 256, 0, stream>>>(pts, minarr, cnt, pix_i, ticket, out);
}

// Round 6
// 48.803 us; speedup vs baseline: 2.0516x; 2.0516x over previous
//
#include <hip/hip_runtime.h>

#define HH 80
#define WW 80
#define IMG (HH * WW)             // 6400
#define NV ((HH - 1) * WW)        // 6320 vertical edge slots
#define NPTS (NV + HH * (WW - 1)) // 12640 edge slots per image
#define NPIX (2 * IMG)            // 12800
#define BIGF 1.0e10f
#define INVC 1.0e7f
#define EPSF 1e-8f
#define QSCALE 131072.0f          // 2^17 fixed point (exact-commutative sums)

#define NB 256                    // k_prep grid
#define BLK 256                   // k_min block (4 waves)
#define APT 4                     // A points per thread
#define ACHUNK (BLK * APT)        // 1024
#define ABLOCKS ((NPTS + ACHUNK - 1) / ACHUNK) // 13 worst case; ~7 active after compaction
#define NSLICE 16
#define MAXSLICE ((((NPTS + NSLICE - 1) / NSLICE) + 1) & ~1) // 790

// padded extraction space: 12672 = 198 waves of 64 per set
#define SETPAD 12672
#define EXWAVES (4 * (SETPAD / 64))   // 792
#define PXWAVES (NPIX / 64)           // 200

__device__ __forceinline__ long long wave_reduce_ll(long long v) {
#pragma unroll
  for (int o = 32; o > 0; o >>= 1) {
    int2 p = *(int2*)&v;
    p.x = __shfl_down(p.x, o, 64);
    p.y = __shfl_down(p.y, o, 64);
    v += *(long long*)&p;
  }
  return v;
}

// --------------------------------------------------------------- k_prep
// 256 blocks. minarr init + pixel loss (int64 fixed point, order-invariant) +
// zero-crossing extraction via wave-ballot atomic append. Append ORDER is
// non-deterministic, but every downstream consumer is order-invariant and
// exact (multiset min; int64 sums) -> output bitwise stable.
// cnt / pix_i / ticket are zeroed by the preceding memset node.
__global__ void __launch_bounds__(256) k_prep(
    const float* __restrict__ pred, const float* __restrict__ gt,
    float2* __restrict__ pts, float* __restrict__ minarr,
    int* __restrict__ cnt, unsigned long long* __restrict__ pix_i) {
  int tid = threadIdx.x, lane = tid & 63, wid = tid >> 6;
  int gtid = blockIdx.x * 256 + tid;

  if (gtid < 4 * NPTS) minarr[gtid] = BIGF;

  int gw = blockIdx.x * 4 + wid;
  if (gw < EXWAVES) {
    int set = gw / (SETPAD / 64);
    int idx = (gw - set * (SETPAD / 64)) * 64 + lane;
    const float* s = (set < 2 ? pred : gt) + (set & 1) * IMG;
    float r = 0.f, c = 0.f;
    bool valid = false;
    if (idx < NPTS) {
      if (idx < NV) {
        int i = idx / WW, j = idx - i * WW;
        float v1 = s[i * WW + j], v2 = s[(i + 1) * WW + j];
        c = (float)j;
        if (v1 == 0.f)      { r = (float)i;       valid = true; }
        else if (v2 == 0.f) { r = (float)i + 1.f; valid = true; }
        else {
          r = (float)i + fabsf(v1) / (fabsf(v1) + fabsf(v2) + EPSF);
          valid = (v1 * v2 < 0.f);
        }
      } else {
        int t = idx - NV;
        int i = t / (WW - 1), j = t - i * (WW - 1);
        float h1 = s[i * WW + j], h2 = s[i * WW + j + 1];
        r = (float)i;
        if (h1 == 0.f)      { c = (float)j;       valid = true; }
        else if (h2 == 0.f) { c = (float)j + 1.f; valid = true; }
        else {
          c = (float)j + fabsf(h1) / (fabsf(h1) + fabsf(h2) + EPSF);
          valid = (h1 * h2 < 0.f);
        }
      }
    }
    unsigned long long mask = __ballot(valid);
    int nw = __popcll(mask);
    int base = 0;
    if (lane == 0 && nw) base = atomicAdd(&cnt[set], nw);
    base = __shfl(base, 0, 64);
    if (valid) {
      int lpos = __popcll(mask & ((1ull << lane) - 1ull));
      pts[set * NPTS + base + lpos] = make_float2(r, c);
    }
  } else if (gw < EXWAVES + PXWAVES) {
    int p = (gw - EXWAVES) * 64 + lane;
    float d = fabsf(pred[p] - gt[p]);
    long long q = (long long)(d * QSCALE + 0.5f);
    q = wave_reduce_ll(q);
    if (lane == 0) atomicAdd(pix_i, (unsigned long long)q);
  }
}

// --------------------------------------------------------------- k_min
// dir 0: A=0 B=2 | 1: A=2 B=0 | 2: A=1 B=3 | 3: A=3 B=1
// min over b of (q2 - 2px*qx - 2py*qy); +p2 and sqrt are monotone (sqrt in k_fin).
__global__ void __launch_bounds__(BLK) k_min(
    const float2* __restrict__ pts, float* __restrict__ minarr,
    const int* __restrict__ cnt) {
  int dir = blockIdx.z;
  int Aset = ((dir & 1) << 1) | (dir >> 1);
  int Bset = Aset ^ 2;
  int cntA = cnt[Aset], cntB = cnt[Bset];

  int abase0 = blockIdx.x * ACHUNK;
  if (abase0 >= cntA) return;
  int slicelen = (((cntB + NSLICE - 1) / NSLICE) + 1) & ~1;
  int b0 = blockIdx.y * slicelen;
  if (b0 >= cntB) return;
  int n = min(slicelen, cntB - b0);
  int sn = (n + 1) & ~1;  // pad to even with a dummy far point

  __shared__ float4 tile[MAXSLICE];
  for (int i = threadIdx.x; i < sn; i += BLK) {
    float2 q = (i < n) ? pts[Bset * NPTS + b0 + i] : make_float2(INVC, INVC);
    tile[i] = make_float4(q.x, q.y, fmaf(q.x, q.x, q.y * q.y), 0.f);
  }
  __syncthreads();

  int abase = abase0 + threadIdx.x;
  float nx[APT], ny[APT], p2[APT], m[APT];
#pragma unroll
  for (int i = 0; i < APT; ++i) {
    int a = abase + i * BLK;
    float2 p = (a < cntA) ? pts[Aset * NPTS + a] : make_float2(0.f, 0.f);
    nx[i] = -2.f * p.x;
    ny[i] = -2.f * p.y;
    p2[i] = fmaf(p.x, p.x, p.y * p.y);
    m[i] = 3.0e38f;
  }

#pragma unroll 2
  for (int b = 0; b < sn; b += 2) {
    float4 q0 = tile[b];
    float4 q1 = tile[b + 1];
#pragma unroll
    for (int i = 0; i < APT; ++i) {
      float t0 = fmaf(ny[i], q0.y, fmaf(nx[i], q0.x, q0.z));
      float t1 = fmaf(ny[i], q1.y, fmaf(nx[i], q1.x, q1.z));
      m[i] = fminf(fminf(t0, t1), m[i]);   // -> v_min3_f32
    }
  }

#pragma unroll
  for (int i = 0; i < APT; ++i) {
    int a = abase + i * BLK;
    if (a < cntA) {
      float d2 = fmaxf(m[i] + p2[i], 0.f);
      // non-negative floats order as uint bit patterns; min is order-exact
      atomicMin((unsigned int*)&minarr[Aset * NPTS + a], __float_as_uint(d2));
    }
  }
}

// --------------------------------------------------------------- k_fin
// 16 blocks (4 per set): exact int64 partial sums of round(sqrt(d2)*2^17),
// device-scope atomicAdd (order-independent, bit-exact). Ticketed last block
// combines and writes the two outputs.
__global__ void __launch_bounds__(256) k_fin(
    const float* __restrict__ minarr, const int* __restrict__ cnt,
    const unsigned long long* __restrict__ pix_i,
    unsigned long long* __restrict__ sum_i,
    unsigned int* __restrict__ ticket, float* __restrict__ out) {
  int set = blockIdx.x >> 2, q = blockIdx.x & 3;
  int tid = threadIdx.x, lane = tid & 63;
  int n = cnt[set];

  long long ls = 0;
  for (int i = q * 256 + tid; i < n; i += 1024) {
    float d = sqrtf(minarr[set * NPTS + i]);
    ls += (long long)(d * QSCALE + 0.5f);
  }
  ls = wave_reduce_ll(ls);
  if (lane == 0) atomicAdd(&sum_i[set], (unsigned long long)ls);
  __syncthreads();

  if (tid == 0) {
    __threadfence();
    unsigned int t = atomicAdd(ticket, 1u);
    if (t == 15u) {  // all 16 blocks' adds complete (device-scope atomics)
      const float iq = 1.0f / QSCALE;
      float ss[4];
      for (int k = 0; k < 4; ++k)
        ss[k] = (float)((long long)atomicAdd(&sum_i[k], 0ull)) * iq;
      float n0 = fmaxf((float)cnt[0], 1.f), n1 = fmaxf((float)cnt[1], 1.f);
      float n2 = fmaxf((float)cnt[2], 1.f), n3 = fmaxf((float)cnt[3], 1.f);
      float ch0 = -ss[0] / n0 + ss[2] / n2;
      float ch1 = -ss[1] / n1 + ss[3] / n3;
      out[0] = (float)(long long)(*pix_i) * iq / (float)NPIX;
      out[1] = 0.5f * (ch0 + ch1);
    }
  }
}

extern "C" void kernel_launch(void* const* d_in, const int* in_sizes, int n_in,
                              void* d_out, int out_size, void* d_ws, size_t ws_size,
                              hipStream_t stream) {
  const float* pred = (const float*)d_in[0];
  const float* gt   = (const float*)d_in[1];
  float* out = (float*)d_out;

  // ws: [0..255] scalars (memset to 0 each call) | 4*NPTS float2 pts | 4*NPTS float mins
  int* cnt = (int*)d_ws;                                               // @0
  unsigned int* ticket = (unsigned int*)((char*)d_ws + 16);            // @16
  unsigned long long* pix_i = (unsigned long long*)((char*)d_ws + 24); // @24
  unsigned long long* sum_i = (unsigned long long*)((char*)d_ws + 32); // @32..63
  float2* pts   = (float2*)((char*)d_ws + 256);
  float* minarr = (float*)((char*)d_ws + 256 + sizeof(float2) * 4 * NPTS);

  hipMemsetAsync(d_ws, 0, 256, stream);
  k_prep<<<NB, 256, 0, stream>>>(pred, gt, pts, minarr, cnt, pix_i);
  k_min<<<dim3(ABLOCKS, NSLICE, 4), BLK, 0, stream>>>(pts, minarr, cnt);
  k_fin<<<16, 256, 0, stream>>>(minarr, cnt, pix_i, sum_i, ticket, out);
}